// Round 2
// baseline (380.763 us; speedup 1.0000x reference)
//
#include <hip/hip_runtime.h>
#include <hip/hip_bf16.h>

// ---- problem constants (B=4, T=4096, D=1024, SPAN=128) ----
#define BB 4
#define TT 4096
#define DD 1024
#define SS 128
#define NBLK 32          // T / SPAN
#define MM (BB*TT)       // 16384 rows

typedef __attribute__((ext_vector_type(8))) short bf16x8;  // 8 bf16 = 4 VGPRs
typedef __attribute__((ext_vector_type(4))) short s16x4;
typedef __attribute__((ext_vector_type(4))) float f32x4;
typedef __attribute__((ext_vector_type(4))) int   i32x4;   // 16B staging chunk

__device__ __forceinline__ short f2bf(float f) {
    union { float f; unsigned u; } cv; cv.f = f;
    unsigned u = cv.u;
    u += 0x7fffu + ((u >> 16) & 1u);   // RNE
    return (short)(u >> 16);
}

// ============================================================
// K0: fp32 -> bf16 cast (inputs are float32 per reference dtype)
// ============================================================
__global__ __launch_bounds__(256) void cast_f32_bf16(
    const float* __restrict__ src, short* __restrict__ dst)
{
    const int i = (blockIdx.x * 256 + threadIdx.x) * 4;
    const float4 v = *(const float4*)(src + i);
    s16x4 o;
    o.x = f2bf(v.x); o.y = f2bf(v.y); o.z = f2bf(v.z); o.w = f2bf(v.w);
    *(s16x4*)(dst + i) = o;
}

// ============================================================
// K1: Y = X @ W^T + bias   (M=16384, N=1024, K=1024, bf16 in, bf16 out)
// SWAP=false: Y stored [M, 1024] (q, k)
// SWAP=true : Y stored transposed as vT [B, 1024, 4096]
//             (swap MFMA operands -> acc holds C^T, stores stay coalesced)
// ============================================================
template<bool SWAP>
__global__ __launch_bounds__(256) void proj_gemm(
    const short* __restrict__ X,
    const short* __restrict__ W,
    const float* __restrict__ bias,   // fp32 bias
    short* __restrict__ Y)
{
    constexpr int BK = 32, LD = 40;   // +8 pad: 80B row stride -> 2-way banks (free)
    __shared__ short As[128 * LD];
    __shared__ short Bs[128 * LD];

    const int tid  = threadIdx.x;
    const int m0   = blockIdx.y * 128;
    const int n0   = blockIdx.x * 128;
    const int wv   = tid >> 6, lane = tid & 63;
    const int wm   = wv >> 1,  wn   = wv & 1;
    const int quad = lane >> 4, c16 = lane & 15;

    f32x4 acc[4][4];
#pragma unroll
    for (int i = 0; i < 4; i++)
#pragma unroll
        for (int j = 0; j < 4; j++) acc[i][j] = (f32x4){0.f, 0.f, 0.f, 0.f};

    const int ar0  = tid >> 2;          // 0..63
    const int ac0  = (tid & 3) * 8;     // 0,8,16,24

    for (int k0 = 0; k0 < DD; k0 += BK) {
        i32x4 a0 = *(const i32x4*)(X + (m0 + ar0) * DD + k0 + ac0);
        i32x4 a1 = *(const i32x4*)(X + (m0 + ar0 + 64) * DD + k0 + ac0);
        i32x4 b0 = *(const i32x4*)(W + (n0 + ar0) * DD + k0 + ac0);
        i32x4 b1 = *(const i32x4*)(W + (n0 + ar0 + 64) * DD + k0 + ac0);
        __syncthreads();
        *(i32x4*)(As + ar0 * LD + ac0)        = a0;
        *(i32x4*)(As + (ar0 + 64) * LD + ac0) = a1;
        *(i32x4*)(Bs + ar0 * LD + ac0)        = b0;
        *(i32x4*)(Bs + (ar0 + 64) * LD + ac0) = b1;
        __syncthreads();

        bf16x8 af[4], bfr[4];
#pragma unroll
        for (int i = 0; i < 4; i++)
            af[i] = *(const bf16x8*)(As + (wm * 64 + i * 16 + c16) * LD + quad * 8);
#pragma unroll
        for (int j = 0; j < 4; j++)
            bfr[j] = *(const bf16x8*)(Bs + (wn * 64 + j * 16 + c16) * LD + quad * 8);
#pragma unroll
        for (int i = 0; i < 4; i++)
#pragma unroll
            for (int j = 0; j < 4; j++) {
                if (SWAP)
                    acc[i][j] = __builtin_amdgcn_mfma_f32_16x16x32_bf16(bfr[j], af[i], acc[i][j], 0, 0, 0);
                else
                    acc[i][j] = __builtin_amdgcn_mfma_f32_16x16x32_bf16(af[i], bfr[j], acc[i][j], 0, 0, 0);
            }
    }

    if (!SWAP) {
        // C layout: row = quad*4 + r, col = c16   (m89/m91 verified)
#pragma unroll
        for (int j = 0; j < 4; j++) {
            const int col = n0 + wn * 64 + j * 16 + c16;
            const float bc = bias[col];
#pragma unroll
            for (int i = 0; i < 4; i++) {
                const int row = m0 + wm * 64 + i * 16 + quad * 4;
#pragma unroll
                for (int r = 0; r < 4; r++)
                    Y[(row + r) * DD + col] = f2bf(acc[i][j][r] + bc);
            }
        }
    } else {
        // acc = C^T: row = d (n-tile j), col = t (m-tile i)
        const int b  = m0 >> 12;      // m0 / 4096
        const int t0 = m0 & 4095;
#pragma unroll
        for (int j = 0; j < 4; j++) {
#pragma unroll
            for (int r = 0; r < 4; r++) {
                const int drow = n0 + wn * 64 + j * 16 + quad * 4 + r;
                const float bc = bias[drow];
#pragma unroll
                for (int i = 0; i < 4; i++) {
                    const int tcol = t0 + wm * 64 + i * 16 + c16;
                    Y[(b * DD + drow) * TT + tcol] = f2bf(acc[i][j][r] + bc);
                }
            }
        }
    }
}

// ============================================================
// K2: scores + mask + softmax -> w  (bf16, [B*NB*128, 256])
// grid (2 q-halves, 128 b*n), 256 thr (4 waves); wave owns 16 full rows.
// ============================================================
__global__ __launch_bounds__(256) void score_softmax(
    const short* __restrict__ Q,   // [16384, 1024]
    const short* __restrict__ K,   // [16384, 1024]
    short* __restrict__ Wt)        // [B*NB*128, 256]
{
    constexpr int LD = 72;         // 64 + 8 pad
    __shared__ short Qs[64 * LD];
    __shared__ short Ks[256 * LD];

    const int tid  = threadIdx.x;
    const int qh   = blockIdx.x;           // 0..1 (q rows 0-63 / 64-127)
    const int bn   = blockIdx.y;           // 0..127
    const int b    = bn >> 5, n = bn & 31;
    const int wv   = tid >> 6, lane = tid & 63;
    const int quad = lane >> 4, c16 = lane & 15;

    f32x4 acc[16];
#pragma unroll
    for (int j = 0; j < 16; j++) acc[j] = (f32x4){0.f, 0.f, 0.f, 0.f};

    const int qrow_base = b * TT + n * SS + qh * 64;
    const int krow_base = b * TT + n * SS - SS;   // may dip below b*TT for n==0
    const int bstart    = b * TT;

    const int qr = tid >> 3;            // 0..31
    const int qc = (tid & 7) * 8;       // 0..56

    for (int d0 = 0; d0 < DD; d0 += 64) {
        i32x4 qv0 = *(const i32x4*)(Q + (qrow_base + qr) * DD + d0 + qc);
        i32x4 qv1 = *(const i32x4*)(Q + (qrow_base + qr + 32) * DD + d0 + qc);
        i32x4 kv[8];
#pragma unroll
        for (int s = 0; s < 8; s++) {
            int grow = krow_base + qr + s * 32;
            if (grow < bstart) grow = bstart;   // n==0 pad region (masked later)
            kv[s] = *(const i32x4*)(K + grow * DD + d0 + qc);
        }
        __syncthreads();
        *(i32x4*)(Qs + qr * LD + qc)        = qv0;
        *(i32x4*)(Qs + (qr + 32) * LD + qc) = qv1;
#pragma unroll
        for (int s = 0; s < 8; s++)
            *(i32x4*)(Ks + (qr + s * 32) * LD + qc) = kv[s];
        __syncthreads();

#pragma unroll
        for (int ks = 0; ks < 2; ks++) {
            bf16x8 a = *(const bf16x8*)(Qs + (wv * 16 + c16) * LD + ks * 32 + quad * 8);
#pragma unroll
            for (int j = 0; j < 16; j++) {
                bf16x8 bfr = *(const bf16x8*)(Ks + (j * 16 + c16) * LD + ks * 32 + quad * 8);
                acc[j] = __builtin_amdgcn_mfma_f32_16x16x32_bf16(a, bfr, acc[j], 0, 0, 0);
            }
        }
    }

    const float scale = 0.03125f;   // 1/sqrt(1024)
#pragma unroll
    for (int r = 0; r < 4; r++) {
        const int q_idx = qh * 64 + wv * 16 + quad * 4 + r;     // 0..127
        float mx = -3.0e38f;
#pragma unroll
        for (int j = 0; j < 16; j++) {
            const int k_idx = j * 16 + c16;                      // 0..255
            const int rel = k_idx - SS - q_idx;
            const bool valid = (rel <= 0) & (rel > -SS) & ((n > 0) | (k_idx >= SS));
            const float sv = valid ? acc[j][r] * scale : -3.0e38f;
            acc[j][r] = sv;
            mx = fmaxf(mx, sv);
        }
#pragma unroll
        for (int o = 1; o < 16; o <<= 1) mx = fmaxf(mx, __shfl_xor(mx, o));
        float sm = 0.f;
#pragma unroll
        for (int j = 0; j < 16; j++) {
            const float p = __expf(acc[j][r] - mx);   // masked -> exp(-huge) = 0
            acc[j][r] = p;
            sm += p;
        }
#pragma unroll
        for (int o = 1; o < 16; o <<= 1) sm += __shfl_xor(sm, o);
        const float inv = 1.0f / sm;
        const int orow = (bn * SS + q_idx) * 256;
#pragma unroll
        for (int j = 0; j < 16; j++)
            Wt[orow + j * 16 + c16] = f2bf(acc[j][r] * inv);
    }
}

// ============================================================
// K3: out = w @ vv   (per bn: M=128 q, N=1024 d, K=256 keys), fp32 out
// A = w [128,256] row-major; B = vT rows (ldb = T) -> B^T GEMM.
// ============================================================
__global__ __launch_bounds__(256) void pv_gemm(
    const short* __restrict__ Wt,   // [B*NB*128, 256]
    const short* __restrict__ VT,   // [B, 1024, 4096]
    float* __restrict__ O)          // [16384, 1024] fp32
{
    constexpr int BK = 32, LD = 40;
    __shared__ short As[128 * LD];
    __shared__ short Bs[128 * LD];

    const int tid  = threadIdx.x;
    const int bn   = blockIdx.y;
    const int b    = bn >> 5, n = bn & 31;
    const int d0   = blockIdx.x * 128;
    const int wv   = tid >> 6, lane = tid & 63;
    const int wm   = wv >> 1,  wn   = wv & 1;
    const int quad = lane >> 4, c16 = lane & 15;

    f32x4 acc[4][4];
#pragma unroll
    for (int i = 0; i < 4; i++)
#pragma unroll
        for (int j = 0; j < 4; j++) acc[i][j] = (f32x4){0.f, 0.f, 0.f, 0.f};

    const int ar0 = tid >> 2;
    const int ac0 = (tid & 3) * 8;
    const int tk0 = n * SS - SS;

    for (int k0 = 0; k0 < 256; k0 += BK) {
        i32x4 a0 = *(const i32x4*)(Wt + (bn * SS + ar0) * 256 + k0 + ac0);
        i32x4 a1 = *(const i32x4*)(Wt + (bn * SS + ar0 + 64) * 256 + k0 + ac0);
        int t = tk0 + k0 + ac0;
        if (t < 0) t = 0;   // n==0 pad keys: w==0 there, value irrelevant
        i32x4 b0 = *(const i32x4*)(VT + (b * DD + d0 + ar0) * TT + t);
        i32x4 b1 = *(const i32x4*)(VT + (b * DD + d0 + ar0 + 64) * TT + t);
        __syncthreads();
        *(i32x4*)(As + ar0 * LD + ac0)        = a0;
        *(i32x4*)(As + (ar0 + 64) * LD + ac0) = a1;
        *(i32x4*)(Bs + ar0 * LD + ac0)        = b0;
        *(i32x4*)(Bs + (ar0 + 64) * LD + ac0) = b1;
        __syncthreads();

        bf16x8 af[4], bfr[4];
#pragma unroll
        for (int i = 0; i < 4; i++)
            af[i] = *(const bf16x8*)(As + (wm * 64 + i * 16 + c16) * LD + quad * 8);
#pragma unroll
        for (int j = 0; j < 4; j++)
            bfr[j] = *(const bf16x8*)(Bs + (wn * 64 + j * 16 + c16) * LD + quad * 8);
#pragma unroll
        for (int i = 0; i < 4; i++)
#pragma unroll
            for (int j = 0; j < 4; j++)
                acc[i][j] = __builtin_amdgcn_mfma_f32_16x16x32_bf16(af[i], bfr[j], acc[i][j], 0, 0, 0);
    }

#pragma unroll
    for (int j = 0; j < 4; j++) {
        const int col = d0 + wn * 64 + j * 16 + c16;
#pragma unroll
        for (int i = 0; i < 4; i++) {
            const int row = n * SS + wm * 64 + i * 16 + quad * 4;
#pragma unroll
            for (int r = 0; r < 4; r++)
                O[(size_t)(b * TT + row + r) * DD + col] = acc[i][j][r];
        }
    }
}

// ============================================================
extern "C" void kernel_launch(void* const* d_in, const int* in_sizes, int n_in,
                              void* d_out, int out_size, void* d_ws, size_t ws_size,
                              hipStream_t stream) {
    const float* x  = (const float*)d_in[0];
    const float* Wq = (const float*)d_in[1];
    const float* bq = (const float*)d_in[2];
    const float* Wk = (const float*)d_in[3];
    const float* bk = (const float*)d_in[4];
    const float* Wv = (const float*)d_in[5];
    const float* bv = (const float*)d_in[6];
    float* out = (float*)d_out;

    char* ws = (char*)d_ws;
    const size_t SZ = (size_t)MM * DD * 2;     // 33,554,432 B (bf16 [16384,1024])
    const size_t WZ = (size_t)DD * DD * 2;     //  2,097,152 B (bf16 [1024,1024])
    short* q   = (short*)(ws);
    short* k   = (short*)(ws + SZ);
    short* vT  = (short*)(ws + 2 * SZ);
    short* w   = (short*)(ws + 3 * SZ);        // 8,388,608 B
    short* xb  = (short*)(ws + 3 * SZ + (size_t)8 * 1024 * 1024);
    short* wqb = (short*)((char*)xb + SZ);
    short* wkb = (short*)((char*)xb + SZ + WZ);
    short* wvb = (short*)((char*)xb + SZ + 2 * WZ);
    // total: 3*33.5 + 8.4 + 33.5 + 3*2.1 MB ~= 149 MB of d_ws

    dim3 blk(256);
    cast_f32_bf16<<<MM * DD / 1024, blk, 0, stream>>>(x,  xb);
    cast_f32_bf16<<<DD * DD / 1024, blk, 0, stream>>>(Wq, wqb);
    cast_f32_bf16<<<DD * DD / 1024, blk, 0, stream>>>(Wk, wkb);
    cast_f32_bf16<<<DD * DD / 1024, blk, 0, stream>>>(Wv, wvb);

    dim3 g1(DD / 128, MM / 128);               // (8, 128)
    proj_gemm<false><<<g1, blk, 0, stream>>>(xb, wqb, bq, q);
    proj_gemm<false><<<g1, blk, 0, stream>>>(xb, wkb, bk, k);
    proj_gemm<true ><<<g1, blk, 0, stream>>>(xb, wvb, bv, vT);

    score_softmax<<<dim3(2, BB * NBLK), blk, 0, stream>>>(q, k, w);

    pv_gemm<<<dim3(DD / 128, BB * NBLK), blk, 0, stream>>>(w, vT, out);
}

// Round 3
// 344.885 us; speedup vs baseline: 1.1040x; 1.1040x over previous
//
#include <hip/hip_runtime.h>
#include <hip/hip_bf16.h>

// ---- problem constants (B=4, T=4096, D=1024, SPAN=128) ----
#define BB 4
#define TT 4096
#define DD 1024
#define SS 128
#define NBLK 32          // T / SPAN
#define MM (BB*TT)       // 16384 rows

typedef __attribute__((ext_vector_type(8))) short bf16x8;  // 8 bf16 = 4 VGPRs
typedef __attribute__((ext_vector_type(4))) short s16x4;
typedef __attribute__((ext_vector_type(4))) float f32x4;
typedef __attribute__((ext_vector_type(4))) int   i32x4;

__device__ __forceinline__ short f2bf(float f) {
    union { float f; unsigned u; } cv; cv.f = f;
    unsigned u = cv.u;
    u += 0x7fffu + ((u >> 16) & 1u);   // RNE
    return (short)(u >> 16);
}

// direct global->LDS DMA, 16B per lane (m97: the 517->874 TF step)
__device__ __forceinline__ void gload16(const short* g, short* l) {
    __builtin_amdgcn_global_load_lds(
        (const __attribute__((address_space(1))) void*)g,
        (__attribute__((address_space(3))) void*)l, 16, 0, 0);
}

// ============================================================
// K0a: x fp32 -> bf16
// ============================================================
__global__ __launch_bounds__(256) void cast_f32_bf16(
    const float* __restrict__ src, short* __restrict__ dst)
{
    const int i = (blockIdx.x * 256 + threadIdx.x) * 4;
    const float4 v = *(const float4*)(src + i);
    s16x4 o;
    o.x = f2bf(v.x); o.y = f2bf(v.y); o.z = f2bf(v.z); o.w = f2bf(v.w);
    *(s16x4*)(dst + i) = o;
}

// K0b: all three weight matrices in one launch (grid.y selects src)
__global__ __launch_bounds__(256) void cast_w3(
    const float* __restrict__ a, const float* __restrict__ b,
    const float* __restrict__ c, short* __restrict__ dst)
{
    const float* src = (blockIdx.y == 0) ? a : (blockIdx.y == 1) ? b : c;
    short* d = dst + (size_t)blockIdx.y * DD * DD;
    const int i = (blockIdx.x * 256 + threadIdx.x) * 4;
    const float4 v = *(const float4*)(src + i);
    s16x4 o;
    o.x = f2bf(v.x); o.y = f2bf(v.y); o.z = f2bf(v.z); o.w = f2bf(v.w);
    *(s16x4*)(d + i) = o;
}

// ============================================================
// K1: Y = X @ W^T + bias  (M=16384, N=1024, K=1024, bf16)
// m97 structure: unpadded [128][32] LDS, global_load_lds x16B.
// Flat 1024-block grid with XCD swizzle: all 8 n-tiles of an
// m-tile stay on one XCD -> X fetched ~once device-wide.
// SWAP=true stores Y^T as vT [B,1024,4096] via operand swap.
// ============================================================
template<bool SWAP>
__global__ __launch_bounds__(256) void proj_gemm(
    const short* __restrict__ X,
    const short* __restrict__ W,
    const float* __restrict__ bias,
    short* __restrict__ Y)
{
    __shared__ short As[128 * 32];
    __shared__ short Bs[128 * 32];

    const int tid = threadIdx.x;
    const int l   = blockIdx.x;
    // xcd = l&7 (round-robin); XCD j owns m-tiles [16j,16j+16), n fastest
    const int m0 = (((l & 7) << 4) | (l >> 6)) * 128;
    const int n0 = ((l >> 3) & 7) * 128;

    const int wv   = tid >> 6, lane = tid & 63;
    const int wm   = wv >> 1,  wn   = wv & 1;
    const int quad = lane >> 4, c16 = lane & 15;
    const int srow = lane >> 2;          // row within 16-row chunk
    const int scol = (lane & 3) * 8;     // element col within 32

    f32x4 acc[4][4];
#pragma unroll
    for (int i = 0; i < 4; i++)
#pragma unroll
        for (int j = 0; j < 4; j++) acc[i][j] = (f32x4){0.f, 0.f, 0.f, 0.f};

    for (int k0 = 0; k0 < DD; k0 += 32) {
        __syncthreads();
#pragma unroll
        for (int s = 0; s < 2; s++) {
            const int c   = wv * 2 + s;          // chunk 0..7 (A) and (B)
            const int row = c * 16 + srow;       // 0..127
            gload16(X + (m0 + row) * DD + k0 + scol, As + row * 32 + scol);
            gload16(W + (n0 + row) * DD + k0 + scol, Bs + row * 32 + scol);
        }
        __syncthreads();

        bf16x8 af[4], bfr[4];
#pragma unroll
        for (int i = 0; i < 4; i++)
            af[i] = *(const bf16x8*)(As + (wm * 64 + i * 16 + c16) * 32 + quad * 8);
#pragma unroll
        for (int j = 0; j < 4; j++)
            bfr[j] = *(const bf16x8*)(Bs + (wn * 64 + j * 16 + c16) * 32 + quad * 8);
#pragma unroll
        for (int i = 0; i < 4; i++)
#pragma unroll
            for (int j = 0; j < 4; j++) {
                if (SWAP)
                    acc[i][j] = __builtin_amdgcn_mfma_f32_16x16x32_bf16(bfr[j], af[i], acc[i][j], 0, 0, 0);
                else
                    acc[i][j] = __builtin_amdgcn_mfma_f32_16x16x32_bf16(af[i], bfr[j], acc[i][j], 0, 0, 0);
            }
    }

    if (!SWAP) {
        // C layout: row = quad*4 + r, col = c16
#pragma unroll
        for (int j = 0; j < 4; j++) {
            const int col = n0 + wn * 64 + j * 16 + c16;
            const float bc = bias[col];
#pragma unroll
            for (int i = 0; i < 4; i++) {
                const int row = m0 + wm * 64 + i * 16 + quad * 4;
#pragma unroll
                for (int r = 0; r < 4; r++)
                    Y[(row + r) * DD + col] = f2bf(acc[i][j][r] + bc);
            }
        }
    } else {
        // acc = C^T: reg row = d, lane col = t
        const int b  = m0 >> 12;
        const int t0 = m0 & 4095;
#pragma unroll
        for (int j = 0; j < 4; j++) {
#pragma unroll
            for (int r = 0; r < 4; r++) {
                const int drow = n0 + wn * 64 + j * 16 + quad * 4 + r;
                const float bc = bias[drow];
#pragma unroll
                for (int i = 0; i < 4; i++) {
                    const int tcol = t0 + wm * 64 + i * 16 + c16;
                    Y[(b * DD + drow) * TT + tcol] = f2bf(acc[i][j][r] + bc);
                }
            }
        }
    }
}

// ============================================================
// K2: scores + mask + softmax -> w  (bf16, [B*NB*128, 256])
// ============================================================
__global__ __launch_bounds__(256) void score_softmax(
    const short* __restrict__ Q,
    const short* __restrict__ K,
    short* __restrict__ Wt)
{
    constexpr int LD = 72;
    __shared__ short Qs[64 * LD];
    __shared__ short Ks[256 * LD];

    const int tid  = threadIdx.x;
    const int qh   = blockIdx.x;
    const int bn   = blockIdx.y;
    const int b    = bn >> 5, n = bn & 31;
    const int wv   = tid >> 6, lane = tid & 63;
    const int quad = lane >> 4, c16 = lane & 15;

    f32x4 acc[16];
#pragma unroll
    for (int j = 0; j < 16; j++) acc[j] = (f32x4){0.f, 0.f, 0.f, 0.f};

    const int qrow_base = b * TT + n * SS + qh * 64;
    const int krow_base = b * TT + n * SS - SS;
    const int bstart    = b * TT;

    const int qr = tid >> 3;
    const int qc = (tid & 7) * 8;

    for (int d0 = 0; d0 < DD; d0 += 64) {
        i32x4 qv0 = *(const i32x4*)(Q + (qrow_base + qr) * DD + d0 + qc);
        i32x4 qv1 = *(const i32x4*)(Q + (qrow_base + qr + 32) * DD + d0 + qc);
        i32x4 kv[8];
#pragma unroll
        for (int s = 0; s < 8; s++) {
            int grow = krow_base + qr + s * 32;
            if (grow < bstart) grow = bstart;
            kv[s] = *(const i32x4*)(K + grow * DD + d0 + qc);
        }
        __syncthreads();
        *(i32x4*)(Qs + qr * LD + qc)        = qv0;
        *(i32x4*)(Qs + (qr + 32) * LD + qc) = qv1;
#pragma unroll
        for (int s = 0; s < 8; s++)
            *(i32x4*)(Ks + (qr + s * 32) * LD + qc) = kv[s];
        __syncthreads();

#pragma unroll
        for (int ks = 0; ks < 2; ks++) {
            bf16x8 a = *(const bf16x8*)(Qs + (wv * 16 + c16) * LD + ks * 32 + quad * 8);
#pragma unroll
            for (int j = 0; j < 16; j++) {
                bf16x8 bfr = *(const bf16x8*)(Ks + (j * 16 + c16) * LD + ks * 32 + quad * 8);
                acc[j] = __builtin_amdgcn_mfma_f32_16x16x32_bf16(a, bfr, acc[j], 0, 0, 0);
            }
        }
    }

    const float scale = 0.03125f;
#pragma unroll
    for (int r = 0; r < 4; r++) {
        const int q_idx = qh * 64 + wv * 16 + quad * 4 + r;
        float mx = -3.0e38f;
#pragma unroll
        for (int j = 0; j < 16; j++) {
            const int k_idx = j * 16 + c16;
            const int rel = k_idx - SS - q_idx;
            const bool valid = (rel <= 0) & (rel > -SS) & ((n > 0) | (k_idx >= SS));
            const float sv = valid ? acc[j][r] * scale : -3.0e38f;
            acc[j][r] = sv;
            mx = fmaxf(mx, sv);
        }
#pragma unroll
        for (int o = 1; o < 16; o <<= 1) mx = fmaxf(mx, __shfl_xor(mx, o));
        float sm = 0.f;
#pragma unroll
        for (int j = 0; j < 16; j++) {
            const float p = __expf(acc[j][r] - mx);
            acc[j][r] = p;
            sm += p;
        }
#pragma unroll
        for (int o = 1; o < 16; o <<= 1) sm += __shfl_xor(sm, o);
        const float inv = 1.0f / sm;
        const int orow = (bn * SS + q_idx) * 256;
#pragma unroll
        for (int j = 0; j < 16; j++)
            Wt[orow + j * 16 + c16] = f2bf(acc[j][r] * inv);
    }
}

// ============================================================
// K3: out = w @ vv  (per bn: M=128, N=1024, K=256), fp32 out
// m97-style staging.
// ============================================================
__global__ __launch_bounds__(256) void pv_gemm(
    const short* __restrict__ Wt,   // [B*NB*128, 256]
    const short* __restrict__ VT,   // [B, 1024, 4096]
    float* __restrict__ O)          // [16384, 1024] fp32
{
    __shared__ short As[128 * 32];
    __shared__ short Bs[128 * 32];

    const int tid  = threadIdx.x;
    const int bn   = blockIdx.y;
    const int b    = bn >> 5, n = bn & 31;
    const int d0   = blockIdx.x * 128;
    const int wv   = tid >> 6, lane = tid & 63;
    const int wm   = wv >> 1,  wn   = wv & 1;
    const int quad = lane >> 4, c16 = lane & 15;
    const int srow = lane >> 2;
    const int scol = (lane & 3) * 8;

    f32x4 acc[4][4];
#pragma unroll
    for (int i = 0; i < 4; i++)
#pragma unroll
        for (int j = 0; j < 4; j++) acc[i][j] = (f32x4){0.f, 0.f, 0.f, 0.f};

    const int tk0 = n * SS - SS;

    for (int k0 = 0; k0 < 256; k0 += 32) {
        __syncthreads();
#pragma unroll
        for (int s = 0; s < 2; s++) {
            const int c   = wv * 2 + s;
            const int row = c * 16 + srow;
            gload16(Wt + (bn * SS + row) * 256 + k0 + scol, As + row * 32 + scol);
            int t = tk0 + k0 + scol;
            if (t < 0) t = 0;   // n==0 pad keys: w==0 there, value irrelevant
            gload16(VT + (b * DD + d0 + row) * TT + t, Bs + row * 32 + scol);
        }
        __syncthreads();

        bf16x8 af[4], bfr[4];
#pragma unroll
        for (int i = 0; i < 4; i++)
            af[i] = *(const bf16x8*)(As + (wm * 64 + i * 16 + c16) * 32 + quad * 8);
#pragma unroll
        for (int j = 0; j < 4; j++)
            bfr[j] = *(const bf16x8*)(Bs + (wn * 64 + j * 16 + c16) * 32 + quad * 8);
#pragma unroll
        for (int i = 0; i < 4; i++)
#pragma unroll
            for (int j = 0; j < 4; j++)
                acc[i][j] = __builtin_amdgcn_mfma_f32_16x16x32_bf16(af[i], bfr[j], acc[i][j], 0, 0, 0);
    }

#pragma unroll
    for (int j = 0; j < 4; j++) {
        const int col = d0 + wn * 64 + j * 16 + c16;
#pragma unroll
        for (int i = 0; i < 4; i++) {
            const int row = n * SS + wm * 64 + i * 16 + quad * 4;
#pragma unroll
            for (int r = 0; r < 4; r++)
                O[(size_t)(b * TT + row + r) * DD + col] = acc[i][j][r];
        }
    }
}

// ============================================================
extern "C" void kernel_launch(void* const* d_in, const int* in_sizes, int n_in,
                              void* d_out, int out_size, void* d_ws, size_t ws_size,
                              hipStream_t stream) {
    const float* x  = (const float*)d_in[0];
    const float* Wq = (const float*)d_in[1];
    const float* bq = (const float*)d_in[2];
    const float* Wk = (const float*)d_in[3];
    const float* bk = (const float*)d_in[4];
    const float* Wv = (const float*)d_in[5];
    const float* bv = (const float*)d_in[6];
    float* out = (float*)d_out;

    char* ws = (char*)d_ws;
    const size_t SZ = (size_t)MM * DD * 2;     // 33,554,432 B (bf16 [16384,1024])
    const size_t WZ = (size_t)DD * DD * 2;     //  2,097,152 B
    short* q   = (short*)(ws);
    short* k   = (short*)(ws + SZ);
    short* vT  = (short*)(ws + 2 * SZ);
    short* w   = (short*)(ws + 3 * SZ);        // 8,388,608 B
    short* xb  = (short*)(ws + 3 * SZ + (size_t)8 * 1024 * 1024);
    short* wqb = (short*)((char*)xb + SZ);
    // wkb, wvb contiguous after wqb (cast_w3 indexes by blockIdx.y)
    short* wkb = (short*)((char*)xb + SZ + WZ);
    short* wvb = (short*)((char*)xb + SZ + 2 * WZ);

    dim3 blk(256);
    cast_f32_bf16<<<MM * DD / 1024, blk, 0, stream>>>(x, xb);
    cast_w3<<<dim3(DD * DD / 1024, 3), blk, 0, stream>>>(Wq, Wk, Wv, wqb);

    proj_gemm<false><<<1024, blk, 0, stream>>>(xb, wqb, bq, q);
    proj_gemm<false><<<1024, blk, 0, stream>>>(xb, wkb, bk, k);
    proj_gemm<true ><<<1024, blk, 0, stream>>>(xb, wvb, bv, vT);

    score_softmax<<<dim3(2, BB * NBLK), blk, 0, stream>>>(q, k, w);

    pv_gemm<<<dim3(DD / 128, BB * NBLK), blk, 0, stream>>>(w, vT, out);
}

// Round 4
// 336.720 us; speedup vs baseline: 1.1308x; 1.0242x over previous
//
#include <hip/hip_runtime.h>
#include <hip/hip_bf16.h>

// ---- problem constants (B=4, T=4096, D=1024, SPAN=128) ----
#define BB 4
#define TT 4096
#define DD 1024
#define SS 128
#define NBLK 32
#define MM (BB*TT)       // 16384 rows

typedef __attribute__((ext_vector_type(8))) short bf16x8;
typedef __attribute__((ext_vector_type(4))) short s16x4;
typedef __attribute__((ext_vector_type(4))) float f32x4;

__device__ __forceinline__ short f2bf(float f) {
    union { float f; unsigned u; } cv; cv.f = f;
    unsigned u = cv.u;
    u += 0x7fffu + ((u >> 16) & 1u);   // RNE
    return (short)(u >> 16);
}

// direct global->LDS DMA, 16B/lane. Contract: LDS dest must equal
// wave-uniform base + lane*16 (true for all call sites below).
__device__ __forceinline__ void gload16(const short* g, short* l) {
    __builtin_amdgcn_global_load_lds(
        (const __attribute__((address_space(1))) void*)g,
        (__attribute__((address_space(3))) void*)l, 16, 0, 0);
}

// ============================================================
// K0a: x fp32 -> bf16
// ============================================================
__global__ __launch_bounds__(256) void cast_f32_bf16(
    const float* __restrict__ src, short* __restrict__ dst)
{
    const int i = (blockIdx.x * 256 + threadIdx.x) * 4;
    const float4 v = *(const float4*)(src + i);
    s16x4 o;
    o.x = f2bf(v.x); o.y = f2bf(v.y); o.z = f2bf(v.z); o.w = f2bf(v.w);
    *(s16x4*)(dst + i) = o;
}

// K0b: three weight matrices, one launch (dst contiguous [3][1024][1024])
__global__ __launch_bounds__(256) void cast_w3(
    const float* __restrict__ a, const float* __restrict__ b,
    const float* __restrict__ c, short* __restrict__ dst)
{
    const float* src = (blockIdx.y == 0) ? a : (blockIdx.y == 1) ? b : c;
    short* d = dst + (size_t)blockIdx.y * DD * DD;
    const int i = (blockIdx.x * 256 + threadIdx.x) * 4;
    const float4 v = *(const float4*)(src + i);
    s16x4 o;
    o.x = f2bf(v.x); o.y = f2bf(v.y); o.z = f2bf(v.z); o.w = f2bf(v.w);
    *(s16x4*)(d + i) = o;
}

// ============================================================
// K1: fused QKV projection.  One GEMM, M=16384, N=3072 (=3x1024).
// n_idx 0..7 -> Q, 8..15 -> K, 16..23 -> V (transposed store via
// operand swap).  XCD swizzle: xcd owns 16 m-tiles x all 24 n-tiles
// -> X fetched ~once device-wide.
// ============================================================
__global__ __launch_bounds__(256) void qkv_gemm(
    const short* __restrict__ X,
    const short* __restrict__ W3,    // [3][1024][1024] bf16
    const float* __restrict__ bq, const float* __restrict__ bk,
    const float* __restrict__ bv,
    short* __restrict__ q, short* __restrict__ k, short* __restrict__ vT)
{
    __shared__ short As[128 * 32];
    __shared__ short Bs[128 * 32];

    const int tid = threadIdx.x;
    const int l   = blockIdx.x;
    const int xcd = l & 7;
    const int rr  = l >> 3;            // 0..383
    const int m0  = (xcd * 16 + (rr & 15)) * 128;
    const int n_idx = rr >> 4;         // 0..23
    const int grp = n_idx >> 3;        // 0=Q 1=K 2=V
    const int n0g = (n_idx & 7) * 128; // col within the 1024-wide group

    const short* W = W3 + (size_t)grp * DD * DD;
    const float* bias = (grp == 0) ? bq : (grp == 1) ? bk : bv;

    const int wv   = tid >> 6, lane = tid & 63;
    const int wm   = wv >> 1,  wn   = wv & 1;
    const int quad = lane >> 4, c16 = lane & 15;
    const int srow = lane >> 2;
    const int scol = (lane & 3) * 8;

    f32x4 acc[4][4];
#pragma unroll
    for (int i = 0; i < 4; i++)
#pragma unroll
        for (int j = 0; j < 4; j++) acc[i][j] = (f32x4){0.f, 0.f, 0.f, 0.f};

    if (grp != 2) {
        for (int k0 = 0; k0 < DD; k0 += 32) {
            __syncthreads();
#pragma unroll
            for (int s = 0; s < 2; s++) {
                const int row = (wv * 2 + s) * 16 + srow;
                gload16(X + (m0 + row) * DD + k0 + scol, As + row * 32 + scol);
                gload16(W + (n0g + row) * DD + k0 + scol, Bs + row * 32 + scol);
            }
            __syncthreads();
            bf16x8 af[4], bfr[4];
#pragma unroll
            for (int i = 0; i < 4; i++)
                af[i] = *(const bf16x8*)(As + (wm * 64 + i * 16 + c16) * 32 + quad * 8);
#pragma unroll
            for (int j = 0; j < 4; j++)
                bfr[j] = *(const bf16x8*)(Bs + (wn * 64 + j * 16 + c16) * 32 + quad * 8);
#pragma unroll
            for (int i = 0; i < 4; i++)
#pragma unroll
                for (int j = 0; j < 4; j++)
                    acc[i][j] = __builtin_amdgcn_mfma_f32_16x16x32_bf16(af[i], bfr[j], acc[i][j], 0, 0, 0);
        }
        short* Y = (grp == 0) ? q : k;
#pragma unroll
        for (int j = 0; j < 4; j++) {
            const int col = n0g + wn * 64 + j * 16 + c16;
            const float bc = bias[col];
#pragma unroll
            for (int i = 0; i < 4; i++) {
                const int row = m0 + wm * 64 + i * 16 + quad * 4;
#pragma unroll
                for (int r = 0; r < 4; r++)
                    Y[(row + r) * DD + col] = f2bf(acc[i][j][r] + bc);
            }
        }
    } else {
        for (int k0 = 0; k0 < DD; k0 += 32) {
            __syncthreads();
#pragma unroll
            for (int s = 0; s < 2; s++) {
                const int row = (wv * 2 + s) * 16 + srow;
                gload16(X + (m0 + row) * DD + k0 + scol, As + row * 32 + scol);
                gload16(W + (n0g + row) * DD + k0 + scol, Bs + row * 32 + scol);
            }
            __syncthreads();
            bf16x8 af[4], bfr[4];
#pragma unroll
            for (int i = 0; i < 4; i++)
                af[i] = *(const bf16x8*)(As + (wm * 64 + i * 16 + c16) * 32 + quad * 8);
#pragma unroll
            for (int j = 0; j < 4; j++)
                bfr[j] = *(const bf16x8*)(Bs + (wn * 64 + j * 16 + c16) * 32 + quad * 8);
#pragma unroll
            for (int i = 0; i < 4; i++)
#pragma unroll
                for (int j = 0; j < 4; j++)
                    acc[i][j] = __builtin_amdgcn_mfma_f32_16x16x32_bf16(bfr[j], af[i], acc[i][j], 0, 0, 0);
        }
        // acc = C^T: reg row = d, lane col = t
        const int b  = m0 >> 12;
        const int t0 = m0 & 4095;
#pragma unroll
        for (int j = 0; j < 4; j++) {
#pragma unroll
            for (int r = 0; r < 4; r++) {
                const int drow = n0g + wn * 64 + j * 16 + quad * 4 + r;
                const float bc = bias[drow];
#pragma unroll
                for (int i = 0; i < 4; i++) {
                    const int tcol = t0 + wm * 64 + i * 16 + c16;
                    vT[(b * DD + drow) * TT + tcol] = f2bf(acc[i][j][r] + bc);
                }
            }
        }
    }
}

// ============================================================
// K2: fused windowed attention per (b, n, qh-half).
// Phase 1: S = Q(64x1024) . K^T(256x1024), masked softmax -> P in LDS
//          (A-fragment layout, per-wave [16][264] padded rows).
// Phase 2: O = P(64x256) . V(256x1024) over 8 d-tiles, V staged from
//          vT with gload16.  No global w round-trip.
// ============================================================
__global__ __launch_bounds__(256) void attn_fused(
    const short* __restrict__ Q,
    const short* __restrict__ Kb,
    const short* __restrict__ VT,    // [B,1024,4096]
    float* __restrict__ O)           // [16384,1024] fp32
{
    __shared__ short lds[20992];          // 41984 B
    short* Qs = lds;                      // [64][32]   (phase 1)
    short* Ks = lds + 2048;               // [256][32]  (phase 1)
    short* Pb = lds;                      // [4][16][264] (phase 2, overlaps)
    short* Vs = lds + 16896;              // [128][32]  (phase 2)

    const int l   = blockIdx.x;
    const int xcd = l & 7;
    const int rr  = l >> 3;               // 0..31
    const int n   = xcd * 4 + (rr & 3);   // contiguous n per XCD (K-window L2 reuse)
    const int qh  = (rr >> 2) & 1;
    const int b   = rr >> 3;

    const int tid  = threadIdx.x;
    const int wv   = tid >> 6, lane = tid & 63;
    const int quad = lane >> 4, c16 = lane & 15;
    const int srow = tid >> 2;            // 0..63
    const int scol = (tid & 3) * 8;

    const int qrow   = b * TT + n * SS + qh * 64;
    const int krow   = b * TT + n * SS - SS;
    const int bstart = b * TT;

    f32x4 acc[16];
#pragma unroll
    for (int j = 0; j < 16; j++) acc[j] = (f32x4){0.f, 0.f, 0.f, 0.f};

    // ---- phase 1: QK^T ----
    for (int d0 = 0; d0 < DD; d0 += 32) {
        __syncthreads();
        gload16(Q + (qrow + srow) * DD + d0 + scol, Qs + srow * 32 + scol);
#pragma unroll
        for (int s = 0; s < 4; s++) {
            const int row = srow + s * 64;
            int g = krow + row;
            if (g < bstart) g = bstart;   // n==0 pad rows (masked below)
            gload16(Kb + g * DD + d0 + scol, Ks + row * 32 + scol);
        }
        __syncthreads();
        bf16x8 a = *(const bf16x8*)(Qs + (wv * 16 + c16) * 32 + quad * 8);
#pragma unroll
        for (int j = 0; j < 16; j++) {
            bf16x8 bf = *(const bf16x8*)(Ks + (j * 16 + c16) * 32 + quad * 8);
            acc[j] = __builtin_amdgcn_mfma_f32_16x16x32_bf16(a, bf, acc[j], 0, 0, 0);
        }
    }

    // ---- softmax + P -> LDS (A-fragment layout) ----
    __syncthreads();   // all waves done reading Qs/Ks before P overwrites them
    short* Pw = Pb + wv * (16 * 264);
    const float scale = 0.03125f;   // 1/sqrt(1024)
#pragma unroll
    for (int r = 0; r < 4; r++) {
        const int q_idx = qh * 64 + wv * 16 + quad * 4 + r;   // 0..127
        float mx = -3.0e38f;
#pragma unroll
        for (int j = 0; j < 16; j++) {
            const int k_idx = j * 16 + c16;                    // 0..255
            const int rel = k_idx - SS - q_idx;
            const bool valid = (rel <= 0) & (rel > -SS) & ((n > 0) | (k_idx >= SS));
            const float sv = valid ? acc[j][r] * scale : -3.0e38f;
            acc[j][r] = sv;
            mx = fmaxf(mx, sv);
        }
#pragma unroll
        for (int o = 1; o < 16; o <<= 1) mx = fmaxf(mx, __shfl_xor(mx, o));
        float sm = 0.f;
#pragma unroll
        for (int j = 0; j < 16; j++) {
            const float p = __expf(acc[j][r] - mx);
            acc[j][r] = p;
            sm += p;
        }
#pragma unroll
        for (int o = 1; o < 16; o <<= 1) sm += __shfl_xor(sm, o);
        const float inv = 1.0f / sm;
#pragma unroll
        for (int j = 0; j < 16; j++)
            Pw[(quad * 4 + r) * 264 + j * 16 + c16] = f2bf(acc[j][r] * inv);
    }

    // ---- phase 2: P . V ----
    const int tbase = n * SS - SS;
    for (int d0 = 0; d0 < DD; d0 += 128) {
        f32x4 o8[8];
#pragma unroll
        for (int j = 0; j < 8; j++) o8[j] = (f32x4){0.f, 0.f, 0.f, 0.f};

        for (int k0 = 0; k0 < 256; k0 += 32) {
            __syncthreads();
#pragma unroll
            for (int s = 0; s < 2; s++) {
                const int row = srow + s * 64;        // d-local 0..127
                int t = tbase + k0 + scol;
                if (t < 0) t = 0;                     // n==0 pad keys: P==0 there
                gload16(VT + (size_t)(b * DD + d0 + row) * TT + t,
                        Vs + row * 32 + scol);
            }
            __syncthreads();
            bf16x8 a = *(const bf16x8*)(Pw + c16 * 264 + k0 + quad * 8);
#pragma unroll
            for (int jj = 0; jj < 8; jj++) {
                bf16x8 bf = *(const bf16x8*)(Vs + (jj * 16 + c16) * 32 + quad * 8);
                o8[jj] = __builtin_amdgcn_mfma_f32_16x16x32_bf16(a, bf, o8[jj], 0, 0, 0);
            }
        }
#pragma unroll
        for (int jj = 0; jj < 8; jj++)
#pragma unroll
            for (int r = 0; r < 4; r++)
                O[(size_t)(qrow + wv * 16 + quad * 4 + r) * DD + d0 + jj * 16 + c16] = o8[jj][r];
    }
}

// ============================================================
extern "C" void kernel_launch(void* const* d_in, const int* in_sizes, int n_in,
                              void* d_out, int out_size, void* d_ws, size_t ws_size,
                              hipStream_t stream) {
    const float* x  = (const float*)d_in[0];
    const float* Wq = (const float*)d_in[1];
    const float* bq = (const float*)d_in[2];
    const float* Wk = (const float*)d_in[3];
    const float* bk = (const float*)d_in[4];
    const float* Wv = (const float*)d_in[5];
    const float* bv = (const float*)d_in[6];
    float* out = (float*)d_out;

    char* ws = (char*)d_ws;
    const size_t SZ = (size_t)MM * DD * 2;     // 33,554,432 B
    const size_t WZ = (size_t)DD * DD * 2;     //  2,097,152 B
    short* q   = (short*)(ws);
    short* k   = (short*)(ws + SZ);
    short* vT  = (short*)(ws + 2 * SZ);
    short* xb  = (short*)(ws + 3 * SZ);
    short* w3b = (short*)(ws + 4 * SZ);        // [3][1024][1024] contiguous
    // total: 4*33.5 + 6.3 MB ~= 141 MB of d_ws

    dim3 blk(256);
    cast_f32_bf16<<<MM * DD / 1024, blk, 0, stream>>>(x, xb);
    cast_w3<<<dim3(DD * DD / 1024, 3), blk, 0, stream>>>(Wq, Wk, Wv, w3b);

    qkv_gemm<<<3072, blk, 0, stream>>>(xb, w3b, bq, bk, bv, q, k, vT);

    attn_fused<<<256, blk, 0, stream>>>(q, k, vT, out);
}

// Round 5
// 321.187 us; speedup vs baseline: 1.1855x; 1.0484x over previous
//
#include <hip/hip_runtime.h>
#include <hip/hip_bf16.h>

// ---- problem constants (B=4, T=4096, D=1024, SPAN=128) ----
#define BB 4
#define TT 4096
#define DD 1024
#define SS 128
#define NBLK 32
#define MM (BB*TT)       // 16384 rows

typedef __attribute__((ext_vector_type(8))) short bf16x8;
typedef __attribute__((ext_vector_type(4))) short s16x4;
typedef __attribute__((ext_vector_type(4))) float f32x4;

__device__ __forceinline__ short f2bf(float f) {
    union { float f; unsigned u; } cv; cv.f = f;
    unsigned u = cv.u;
    u += 0x7fffu + ((u >> 16) & 1u);   // RNE
    return (short)(u >> 16);
}

// direct global->LDS DMA, 16B/lane. Contract: LDS dest = wave-uniform
// base + lane*16 (verified for every call site below).
__device__ __forceinline__ void gload16(const short* g, short* l) {
    __builtin_amdgcn_global_load_lds(
        (const __attribute__((address_space(1))) void*)g,
        (__attribute__((address_space(3))) void*)l, 16, 0, 0);
}

// ============================================================
// K0a: x fp32 -> bf16
// ============================================================
__global__ __launch_bounds__(256) void cast_f32_bf16(
    const float* __restrict__ src, short* __restrict__ dst)
{
    const int i = (blockIdx.x * 256 + threadIdx.x) * 4;
    const float4 v = *(const float4*)(src + i);
    s16x4 o;
    o.x = f2bf(v.x); o.y = f2bf(v.y); o.z = f2bf(v.z); o.w = f2bf(v.w);
    *(s16x4*)(dst + i) = o;
}

// K0b: three weight matrices, one launch (dst contiguous [3][1024][1024])
__global__ __launch_bounds__(256) void cast_w3(
    const float* __restrict__ a, const float* __restrict__ b,
    const float* __restrict__ c, short* __restrict__ dst)
{
    const float* src = (blockIdx.y == 0) ? a : (blockIdx.y == 1) ? b : c;
    short* d = dst + (size_t)blockIdx.y * DD * DD;
    const int i = (blockIdx.x * 256 + threadIdx.x) * 4;
    const float4 v = *(const float4*)(src + i);
    s16x4 o;
    o.x = f2bf(v.x); o.y = f2bf(v.y); o.z = f2bf(v.z); o.w = f2bf(v.w);
    *(s16x4*)(d + i) = o;
}

// ============================================================
// K1: fused QKV projection (unchanged from round 4 — at the m97-class
// plateau; restructuring is a separate experiment).
// ============================================================
__global__ __launch_bounds__(256) void qkv_gemm(
    const short* __restrict__ X,
    const short* __restrict__ W3,    // [3][1024][1024] bf16
    const float* __restrict__ bq, const float* __restrict__ bk,
    const float* __restrict__ bv,
    short* __restrict__ q, short* __restrict__ k, short* __restrict__ vT)
{
    __shared__ short As[128 * 32];
    __shared__ short Bs[128 * 32];

    const int tid = threadIdx.x;
    const int l   = blockIdx.x;
    const int xcd = l & 7;
    const int rr  = l >> 3;            // 0..383
    const int m0  = (xcd * 16 + (rr & 15)) * 128;
    const int n_idx = rr >> 4;         // 0..23
    const int grp = n_idx >> 3;        // 0=Q 1=K 2=V
    const int n0g = (n_idx & 7) * 128;

    const short* W = W3 + (size_t)grp * DD * DD;
    const float* bias = (grp == 0) ? bq : (grp == 1) ? bk : bv;

    const int wv   = tid >> 6, lane = tid & 63;
    const int wm   = wv >> 1,  wn   = wv & 1;
    const int quad = lane >> 4, c16 = lane & 15;
    const int srow = lane >> 2;
    const int scol = (lane & 3) * 8;

    f32x4 acc[4][4];
#pragma unroll
    for (int i = 0; i < 4; i++)
#pragma unroll
        for (int j = 0; j < 4; j++) acc[i][j] = (f32x4){0.f, 0.f, 0.f, 0.f};

    if (grp != 2) {
        for (int k0 = 0; k0 < DD; k0 += 32) {
            __syncthreads();
#pragma unroll
            for (int s = 0; s < 2; s++) {
                const int row = (wv * 2 + s) * 16 + srow;
                gload16(X + (m0 + row) * DD + k0 + scol, As + row * 32 + scol);
                gload16(W + (n0g + row) * DD + k0 + scol, Bs + row * 32 + scol);
            }
            __syncthreads();
            bf16x8 af[4], bfr[4];
#pragma unroll
            for (int i = 0; i < 4; i++)
                af[i] = *(const bf16x8*)(As + (wm * 64 + i * 16 + c16) * 32 + quad * 8);
#pragma unroll
            for (int j = 0; j < 4; j++)
                bfr[j] = *(const bf16x8*)(Bs + (wn * 64 + j * 16 + c16) * 32 + quad * 8);
#pragma unroll
            for (int i = 0; i < 4; i++)
#pragma unroll
                for (int j = 0; j < 4; j++)
                    acc[i][j] = __builtin_amdgcn_mfma_f32_16x16x32_bf16(af[i], bfr[j], acc[i][j], 0, 0, 0);
        }
        short* Y = (grp == 0) ? q : k;
#pragma unroll
        for (int j = 0; j < 4; j++) {
            const int col = n0g + wn * 64 + j * 16 + c16;
            const float bc = bias[col];
#pragma unroll
            for (int i = 0; i < 4; i++) {
                const int row = m0 + wm * 64 + i * 16 + quad * 4;
#pragma unroll
                for (int r = 0; r < 4; r++)
                    Y[(row + r) * DD + col] = f2bf(acc[i][j][r] + bc);
            }
        }
    } else {
        for (int k0 = 0; k0 < DD; k0 += 32) {
            __syncthreads();
#pragma unroll
            for (int s = 0; s < 2; s++) {
                const int row = (wv * 2 + s) * 16 + srow;
                gload16(X + (m0 + row) * DD + k0 + scol, As + row * 32 + scol);
                gload16(W + (n0g + row) * DD + k0 + scol, Bs + row * 32 + scol);
            }
            __syncthreads();
            bf16x8 af[4], bfr[4];
#pragma unroll
            for (int i = 0; i < 4; i++)
                af[i] = *(const bf16x8*)(As + (wm * 64 + i * 16 + c16) * 32 + quad * 8);
#pragma unroll
            for (int j = 0; j < 4; j++)
                bfr[j] = *(const bf16x8*)(Bs + (wn * 64 + j * 16 + c16) * 32 + quad * 8);
#pragma unroll
            for (int i = 0; i < 4; i++)
#pragma unroll
                for (int j = 0; j < 4; j++)
                    acc[i][j] = __builtin_amdgcn_mfma_f32_16x16x32_bf16(bfr[j], af[i], acc[i][j], 0, 0, 0);
        }
        const int b  = m0 >> 12;
        const int t0 = m0 & 4095;
#pragma unroll
        for (int j = 0; j < 4; j++) {
#pragma unroll
            for (int r = 0; r < 4; r++) {
                const int drow = n0g + wn * 64 + j * 16 + quad * 4 + r;
                const float bc = bias[drow];
#pragma unroll
                for (int i = 0; i < 4; i++) {
                    const int tcol = t0 + wm * 64 + i * 16 + c16;
                    vT[(b * DD + drow) * TT + tcol] = f2bf(acc[i][j][r] + bc);
                }
            }
        }
    }
}

// ============================================================
// K2: fused windowed attention per (b, n, qh).  1 block/CU -> all
// latency hiding must be intra-block: double-buffered LDS with a
// ONE-barrier prefetch loop (prefetch k+1 issued right after the
// barrier, consumed at the next barrier after a full compute phase).
//
// LDS map (shorts):
//   phase 1: bufA Q[2][64][32]@0, K[2][256][32]@4096; bufB @20480 (+same)
//   P      : @40960, per-wave [16][264]
//   phase 2: V bufs [4][128][32] @0 and @16384 (phase-1 region, after sync)
// ============================================================
__global__ __launch_bounds__(256) void attn_fused(
    const short* __restrict__ Q,
    const short* __restrict__ Kb,
    const short* __restrict__ VT,    // [B,1024,4096]
    float* __restrict__ O)           // [16384,1024] fp32
{
    __shared__ short lds[57856];     // 113 KB

    const int l   = blockIdx.x;
    const int xcd = l & 7;
    const int rr  = l >> 3;               // 0..31
    const int n   = xcd * 4 + (rr & 3);   // both qh of one (b,n) on same XCD
    const int qh  = (rr >> 2) & 1;
    const int b   = rr >> 3;

    const int tid  = threadIdx.x;
    const int wv   = tid >> 6, lane = tid & 63;
    const int quad = lane >> 4, c16 = lane & 15;
    const int srow = tid >> 2;            // 0..63
    const int scol = (tid & 3) * 8;

    const int qrow   = b * TT + n * SS + qh * 64;
    const int krow   = b * TT + n * SS - SS;
    const int bstart = b * TT;

    // ---------------- phase 1: S = Q.K^T, BK=64, dbuf ----------------
    f32x4 acc[16];
#pragma unroll
    for (int j = 0; j < 16; j++) acc[j] = (f32x4){0.f, 0.f, 0.f, 0.f};

    // stage phase-1 buffer: Q[2][64][32] + K[2][256][32] at base qb/kbuf
    auto stage1 = [&](int kk, short* qb, short* kbuf) {
        const int k0 = kk * 64;
#pragma unroll
        for (int ks = 0; ks < 2; ks++) {
            gload16(Q + (qrow + srow) * DD + k0 + ks * 32 + scol,
                    qb + ks * 2048 + srow * 32 + scol);
#pragma unroll
            for (int s = 0; s < 4; s++) {
                const int row = srow + s * 64;
                int g = krow + row;
                if (g < bstart) g = bstart;   // n==0 pad rows (masked below)
                gload16(Kb + g * DD + k0 + ks * 32 + scol,
                        kbuf + ks * 8192 + row * 32 + scol);
            }
        }
    };

    stage1(0, lds, lds + 4096);
    for (int kk = 0; kk < 16; kk++) {
        __syncthreads();                       // drains loads for buf[kk&1]
        if (kk < 15) {
            const int o = ((kk + 1) & 1) * 20480;
            stage1(kk + 1, lds + o, lds + o + 4096);   // in flight during compute
        }
        const int cb = (kk & 1) * 20480;
        const short* qb = lds + cb;
        const short* kbuf = lds + cb + 4096;
#pragma unroll
        for (int ks = 0; ks < 2; ks++) {
            bf16x8 a = *(const bf16x8*)(qb + ks * 2048 + (wv * 16 + c16) * 32 + quad * 8);
#pragma unroll
            for (int j = 0; j < 16; j++) {
                bf16x8 bf = *(const bf16x8*)(kbuf + ks * 8192 + (j * 16 + c16) * 32 + quad * 8);
                acc[j] = __builtin_amdgcn_mfma_f32_16x16x32_bf16(a, bf, acc[j], 0, 0, 0);
            }
        }
    }

    // ---------------- softmax + P -> LDS (A-frag layout) ----------------
    short* Pw = lds + 40960 + wv * (16 * 264);
    const float scale = 0.03125f;   // 1/sqrt(1024)
#pragma unroll
    for (int r = 0; r < 4; r++) {
        const int q_idx = qh * 64 + wv * 16 + quad * 4 + r;   // 0..127
        float mx = -3.0e38f;
#pragma unroll
        for (int j = 0; j < 16; j++) {
            const int k_idx = j * 16 + c16;                    // 0..255
            const int rel = k_idx - SS - q_idx;
            const bool valid = (rel <= 0) & (rel > -SS) & ((n > 0) | (k_idx >= SS));
            const float sv = valid ? acc[j][r] * scale : -3.0e38f;
            acc[j][r] = sv;
            mx = fmaxf(mx, sv);
        }
#pragma unroll
        for (int o = 1; o < 16; o <<= 1) mx = fmaxf(mx, __shfl_xor(mx, o));
        float sm = 0.f;
#pragma unroll
        for (int j = 0; j < 16; j++) {
            const float p = __expf(acc[j][r] - mx);
            acc[j][r] = p;
            sm += p;
        }
#pragma unroll
        for (int o = 1; o < 16; o <<= 1) sm += __shfl_xor(sm, o);
        const float inv = 1.0f / sm;
#pragma unroll
        for (int j = 0; j < 16; j++)
            Pw[(quad * 4 + r) * 264 + j * 16 + c16] = f2bf(acc[j][r] * inv);
    }

    // ---------------- phase 2: O = P.V, dbuf over (d0, k-half) ----------------
    const int tbase = n * SS - SS;
    // stage half-window: V[d0..d0+128][kh*128 .. +128] as 4 [128][32] chunks
    auto stage2 = [&](int s, short* vbuf) {
        const int d0 = (s >> 1) * 128;
        const int kh = (s & 1) * 128;
#pragma unroll
        for (int kc = 0; kc < 4; kc++) {
#pragma unroll
            for (int s64 = 0; s64 < 2; s64++) {
                const int row = srow + s64 * 64;     // d-local 0..127
                int t = tbase + kh + kc * 32 + scol;
                if (t < 0) t = 0;                    // n==0 pad keys: P==0 there
                gload16(VT + (size_t)(b * DD + d0 + row) * TT + t,
                        vbuf + kc * 4096 + row * 32 + scol);
            }
        }
    };

    __syncthreads();            // phase-1 LDS region now dead for all waves
    stage2(0, lds);
    f32x4 o8[8];
#pragma unroll
    for (int j = 0; j < 8; j++) o8[j] = (f32x4){0.f, 0.f, 0.f, 0.f};

    for (int s = 0; s < 16; s++) {
        __syncthreads();
        if (s < 15) stage2(s + 1, lds + ((s + 1) & 1) * 16384);
        const short* vbuf = lds + (s & 1) * 16384;
        const int kh = (s & 1) * 128;
#pragma unroll
        for (int kc = 0; kc < 4; kc++) {
            bf16x8 a = *(const bf16x8*)(Pw + c16 * 264 + kh + kc * 32 + quad * 8);
#pragma unroll
            for (int jj = 0; jj < 8; jj++) {
                bf16x8 bf = *(const bf16x8*)(vbuf + kc * 4096 + (jj * 16 + c16) * 32 + quad * 8);
                o8[jj] = __builtin_amdgcn_mfma_f32_16x16x32_bf16(a, bf, o8[jj], 0, 0, 0);
            }
        }
        if (s & 1) {
            const int d0 = (s >> 1) * 128;
#pragma unroll
            for (int jj = 0; jj < 8; jj++) {
#pragma unroll
                for (int r = 0; r < 4; r++)
                    O[(size_t)(qrow + wv * 16 + quad * 4 + r) * DD + d0 + jj * 16 + c16] = o8[jj][r];
                o8[jj] = (f32x4){0.f, 0.f, 0.f, 0.f};
            }
        }
    }
}

// ============================================================
extern "C" void kernel_launch(void* const* d_in, const int* in_sizes, int n_in,
                              void* d_out, int out_size, void* d_ws, size_t ws_size,
                              hipStream_t stream) {
    const float* x  = (const float*)d_in[0];
    const float* Wq = (const float*)d_in[1];
    const float* bq = (const float*)d_in[2];
    const float* Wk = (const float*)d_in[3];
    const float* bk = (const float*)d_in[4];
    const float* Wv = (const float*)d_in[5];
    const float* bv = (const float*)d_in[6];
    float* out = (float*)d_out;

    char* ws = (char*)d_ws;
    const size_t SZ = (size_t)MM * DD * 2;     // 33,554,432 B
    short* q   = (short*)(ws);
    short* k   = (short*)(ws + SZ);
    short* vT  = (short*)(ws + 2 * SZ);
    short* xb  = (short*)(ws + 3 * SZ);
    short* w3b = (short*)(ws + 4 * SZ);        // [3][1024][1024] contiguous

    dim3 blk(256);
    cast_f32_bf16<<<MM * DD / 1024, blk, 0, stream>>>(x, xb);
    cast_w3<<<dim3(DD * DD / 1024, 3), blk, 0, stream>>>(Wq, Wk, Wv, w3b);

    qkv_gemm<<<3072, blk, 0, stream>>>(xb, w3b, bq, bk, bv, q, k, vT);

    attn_fused<<<256, blk, 0, stream>>>(q, k, vT, out);
}